// Round 7
// baseline (860.711 us; speedup 1.0000x reference)
//
#include <hip/hip_runtime.h>
#include <math.h>
#include <stddef.h>

#define NLAYER 24
#define NEMBD  1024
#define NFFN   4096
#define NB     256
#define NT     256            // wave 0 = orchestrator, waves 1-3 = streamers
#define LN_EPS 1e-5f

#define OUT_SA (NEMBD)
#define OUT_SB (NEMBD + NLAYER*NEMBD)
#define OUT_SC (NEMBD + 2*NLAYER*NEMBD)
#define OUT_SD (NEMBD + 3*NLAYER*NEMBD)

#define FLAG_STRIDE 32        // 128 B per block flag line

// LDS float offsets
#define LA    0               // 4096: staged acts (s2: kvr, s4: kfb)
#define LX    4096            // 1024: x / xbuf (live through stage 2)
#define LB    5120            // 1024: sxx (live through stage 4)
#define LD    6144            // 3072: masked vectors
#define LE    9216            // 1024: writer vec 1 (xy / sb_new / xx)
#define LF    10240           // 1024: writer vec 2 (sc_new)
#define LRES  11264           // 32: per-stage results
#define LRFB  11296           // 4: rfb local copy (persists s3->s4)
#define LPART 11300           // 8: LN partials
#define LDS_FLOATS 11312

struct Params {
  const float *x, *state, *ln1w, *ln1b, *ln2w, *ln2b, *td, *tf, *kktk, *vvtv, *rrtr;
  const float *key, *outputv, *tmk, *tmr, *kffn, *rffn, *vffn;
  float *out;
  float *xbuf, *kvr, *sxx, *rfb, *kfb;
  unsigned *flags;
};

__device__ __forceinline__ float wred(float v) {
#pragma unroll
  for (int o = 32; o > 0; o >>= 1) v += __shfl_xor(v, o, 64);
  return v;
}
__device__ __forceinline__ float dot4(float4 a, float4 b) {
  return a.x*b.x + a.y*b.y + a.z*b.z + a.w*b.w;
}
__device__ __forceinline__ float fcomp(float4 v, int j) {   // j must be literal
  return j == 0 ? v.x : (j == 1 ? v.y : (j == 2 ? v.z : v.w));
}
__device__ __forceinline__ float gload(const float* a) {
  return __hip_atomic_load(a, __ATOMIC_RELAXED, __HIP_MEMORY_SCOPE_AGENT);
}
__device__ __forceinline__ void gstore(float* a, float v) {
  __hip_atomic_store(a, v, __ATOMIC_RELAXED, __HIP_MEMORY_SCOPE_AGENT);
}

// raw barrier: drains LDS only (lgkmcnt), leaves global prefetch in flight
__device__ __forceinline__ void lbar() {
  __builtin_amdgcn_sched_barrier(0);
  asm volatile("s_waitcnt lgkmcnt(0)" ::: "memory");
  __builtin_amdgcn_s_barrier();
  __builtin_amdgcn_sched_barrier(0);
}

__global__ void __launch_bounds__(NT, 1)
rwkv_persistent(Params p) {
  const int b    = blockIdx.x;
  const int t    = threadIdx.x;
  const int wid  = t >> 6;
  const int lane = t & 63;
  const bool orch = (wid == 0);
  const int cw   = wid - 1;          // 0..2 for streamer waves
  const int i0   = t * 4;            // elementwise quarter index

  __shared__ float sm[LDS_FLOATS];
  __shared__ unsigned genw;
  volatile unsigned* gw = &genw;

  if (t == 0) genw = 0u;
  __syncthreads();                   // init fence (nothing in flight yet)

  float4 wr[28];                     // weight prefetch (compile-time indexed only)
  float4 pr[6];                      // param prefetch

  // ---------------- prefetch / staging helpers ----------------
  auto load_pr1 = [&](int L) {
    const int o = L * NEMBD + i0;
    pr[0] = *(const float4*)&p.ln1w[o];
    pr[1] = *(const float4*)&p.ln1b[o];
    pr[2] = *(const float4*)&p.state[0 * NLAYER * NEMBD + o];
    pr[3] = *(const float4*)&p.kktk[o];
    pr[4] = *(const float4*)&p.vvtv[o];
    pr[5] = *(const float4*)&p.rrtr[o];
  };
  auto load_pr2 = [&](int L) {
    const int o = L * NEMBD + i0;
    pr[0] = *(const float4*)&p.tf[o];
    pr[1] = *(const float4*)&p.state[1 * NLAYER * NEMBD + o];
    pr[2] = *(const float4*)&p.state[2 * NLAYER * NEMBD + o];
    pr[3] = *(const float4*)&p.td[o];
  };
  auto load_pr3 = [&](int L) {
    const int o = L * NEMBD + i0;
    pr[0] = *(const float4*)&p.ln2w[o];
    pr[1] = *(const float4*)&p.ln2b[o];
    pr[2] = *(const float4*)&p.state[3 * NLAYER * NEMBD + o];
    pr[3] = *(const float4*)&p.tmk[o];
    pr[4] = *(const float4*)&p.tmr[o];
  };
  auto load_wr1 = [&](int L) {       // 4 rows x 4 chunks (streamers only)
    const int r0 = b * 12 + cw * 4;
    const float* W = p.key + (size_t)L * 3 * NEMBD * NEMBD + (size_t)r0 * NEMBD + lane * 4;
#pragma unroll
    for (int q = 0; q < 4; ++q)
#pragma unroll
      for (int jj = 0; jj < 4; ++jj)
        wr[q * 4 + jj] = *(const float4*)&W[(size_t)q * NEMBD + jj * 256];
  };
  auto load_wr2 = [&](int L) {       // 2/1/1 rows x 4
    const int nr = (cw == 0) ? 2 : 1;
    const int rl0 = (cw == 0) ? 0 : (cw + 1);
#pragma unroll
    for (int r = 0; r < 2; ++r) if (r < nr) {
      const float* W = p.outputv + ((size_t)L * NEMBD + b * 4 + rl0 + r) * NEMBD + lane * 4;
#pragma unroll
      for (int jj = 0; jj < 4; ++jj)
        wr[r * 4 + jj] = *(const float4*)&W[jj * 256];
    }
  };
  auto load_wr3 = [&](int L) {       // 7/7/6 rows x 4
#pragma unroll
    for (int e = 0; e < 7; ++e) {
      const int sidx = cw * 7 + e;
      if (sidx < 20) {
        const float* W = (sidx < 16)
          ? p.kffn + ((size_t)L * NFFN  + b * 16 + sidx) * NEMBD
          : p.rffn + ((size_t)L * NEMBD + b * 4 + (sidx - 16)) * NEMBD;
        W += lane * 4;
#pragma unroll
        for (int jj = 0; jj < 4; ++jj)
          wr[e * 4 + jj] = *(const float4*)&W[jj * 256];
      }
    }
  };
  auto load_wr4 = [&](int L) {       // 4 rows x 6/5/5 K-chunks
    const int jbase = (cw == 0) ? 0 : ((cw == 1) ? 6 : 11);
    const int jn    = (cw == 0) ? 6 : 5;
#pragma unroll
    for (int r = 0; r < 4; ++r) {
      const float* W = p.vffn + ((size_t)L * NEMBD + b * 4 + r) * NFFN + lane * 4;
#pragma unroll
      for (int c = 0; c < 6; ++c) if (c < jn)
        wr[r * 6 + c] = *(const float4*)&W[(jbase + c) * 256];
    }
  };
  auto ln_stats = [&](const float xa[4], float& m, float& rs) {
    float s = xa[0] + xa[1] + xa[2] + xa[3];
    float q = xa[0]*xa[0] + xa[1]*xa[1] + xa[2]*xa[2] + xa[3]*xa[3];
    s = wred(s); q = wred(q);
    if (lane == 0) { sm[LPART + wid] = s; sm[LPART + 4 + wid] = q; }
    lbar();
    float ts = sm[LPART+0] + sm[LPART+1] + sm[LPART+2] + sm[LPART+3];
    float tq = sm[LPART+4] + sm[LPART+5] + sm[LPART+6] + sm[LPART+7];
    m = ts * (1.f / NEMBD);
    rs = rsqrtf(tq * (1.f / NEMBD) - m * m + LN_EPS);
  };
  auto spin_ge = [&](unsigned tgt) {
    long c = 0;
    while (*gw < tgt) { __builtin_amdgcn_s_sleep(1); if (++c > (1L << 20)) break; }
    asm volatile("" ::: "memory");
  };
  auto flag_pub = [&](unsigned v) {
    asm volatile("s_waitcnt vmcnt(0)" ::: "memory");   // own stores drained (orch only)
    if (lane == 0)
      __hip_atomic_store(&p.flags[(unsigned)b * FLAG_STRIDE], v,
                         __ATOMIC_RELAXED, __HIP_MEMORY_SCOPE_AGENT);
  };
  auto poll = [&](unsigned v) {
    long c = 0;
    for (;;) {
      bool mine = true;
#pragma unroll
      for (int j = 0; j < 4; ++j) {
        unsigned f = __hip_atomic_load(&p.flags[(unsigned)(lane * 4 + j) * FLAG_STRIDE],
                                       __ATOMIC_RELAXED, __HIP_MEMORY_SCOPE_AGENT);
        mine &= (f >= v);
      }
      if (__all(mine)) break;
      __builtin_amdgcn_s_sleep(1);
      if (++c > (1L << 18)) break;
    }
  };
  auto post_gen = [&](unsigned v) {
    asm volatile("s_waitcnt lgkmcnt(0)" ::: "memory");
    __builtin_amdgcn_sched_barrier(0);
    if (lane == 0) *gw = v;
  };

  // ---------------- prologue ----------------
  if (orch) {
#pragma unroll
    for (int c = 0; c < 4; ++c)
      *(float4*)&sm[LX + lane * 4 + c * 256] = *(const float4*)&p.x[lane * 4 + c * 256];
    load_pr1(0);
    post_gen(1u);
  } else {
    load_pr1(0); load_wr1(0);
  }

  for (int l = 0; l < NLAYER; ++l) {
    const bool w1 = (b == (l * 4 + 0) % NB);
    const bool w2 = (b == (l * 4 + 1) % NB);
    const bool w3 = (b == (l * 4 + 2) % NB);

    // ================= STAGE 1: ln1 + masks + kvr GEMV =================
    {
      const unsigned s = (unsigned)(l * 4 + 1);
      if (!orch) spin_ge(s);
      float4 xv = *(const float4*)&sm[LX + i0];
      float xa[4] = {xv.x, xv.y, xv.z, xv.w};
      float m, rs; ln_stats(xa, m, rs);          // lbar #1
#pragma unroll
      for (int j = 0; j < 4; ++j) {
        int i = i0 + j;
        float xy  = (xa[j] - m) * rs * fcomp(pr[0], j) + fcomp(pr[1], j);
        float sav = fcomp(pr[2], j);
        sm[LD + i]        = xy + fcomp(pr[3], j) * sav;
        sm[LD + 1024 + i] = xy + fcomp(pr[4], j) * sav;
        sm[LD + 2048 + i] = xy + fcomp(pr[5], j) * sav;
        if (w1) sm[LE + i] = xy;
      }
      lbar();                                    // lbar #2: masks ready
      if (!orch) {
        const int r0 = b * 12 + cw * 4;
        const int mb = LD + (r0 >> 10) * 1024;   // 4-row group never straddles
#pragma unroll
        for (int q = 0; q < 4; ++q) {
          float a = 0.f;
#pragma unroll
          for (int jj = 0; jj < 4; ++jj)
            a += dot4(wr[q * 4 + jj], *(const float4*)&sm[mb + lane * 4 + jj * 256]);
          a = wred(a);
          if (lane == 0) sm[LRES + cw * 4 + q] = a;
        }
        load_pr2(l); load_wr2(l);                // next-stage prefetch, in flight
      }
      lbar();                                    // lbar #3: stage end
      if (orch) {
        if (lane < 12) gstore(&p.kvr[b * 12 + lane], sm[LRES + lane]);
        flag_pub(s);
        if (w1) {
#pragma unroll
          for (int c = 0; c < 4; ++c)
            *(float4*)&p.out[OUT_SA + l * NEMBD + lane * 4 + c * 256] =
              *(float4*)&sm[LE + lane * 4 + c * 256];
        }
        poll(s);
#pragma unroll
        for (int c = 0; c < 12; ++c) {
          const int o = lane * 4 + c * 256;
          *(float4*)&sm[LA + o] = make_float4(gload(&p.kvr[o]), gload(&p.kvr[o+1]),
                                              gload(&p.kvr[o+2]), gload(&p.kvr[o+3]));
        }
        load_pr2(l);
        post_gen(s + 1);
      }
    }

    // ================= STAGE 2: wkv combine + outputv GEMV =================
    {
      const unsigned s = (unsigned)(l * 4 + 2);
      if (!orch) spin_ge(s);
      float4 kv = *(const float4*)&sm[LA + i0];
      float4 vv = *(const float4*)&sm[LA + 1024 + i0];
      float4 rv = *(const float4*)&sm[LA + 2048 + i0];
#pragma unroll
      for (int j = 0; j < 4; ++j) {
        float k = fcomp(kv, j), v = fcomp(vv, j), r = fcomp(rv, j);
        float tf = fcomp(pr[0], j), sb = fcomp(pr[1], j), sc = fcomp(pr[2], j);
        float etfk = expf(tf + k);
        float er   = expf(r);
        sm[LD + i0 + j] = (sb + etfk * v) / ((sc + etfk) * (1.f + er));
        if (w2) {
          float ek = expf(k), ed = expf(fcomp(pr[3], j));
          sm[LE + i0 + j] = sb * ed + ek * v;
          sm[LF + i0 + j] = sc * ed + ek;
        }
      }
      lbar();                                    // w vec ready
      if (!orch) {
        const int nr = (cw == 0) ? 2 : 1;
        const int rl0 = (cw == 0) ? 0 : (cw + 1);
#pragma unroll
        for (int r = 0; r < 2; ++r) if (r < nr) {
          float a = 0.f;
#pragma unroll
          for (int jj = 0; jj < 4; ++jj)
            a += dot4(wr[r * 4 + jj], *(const float4*)&sm[LD + lane * 4 + jj * 256]);
          a = wred(a);
          if (lane == 0) sm[LRES + rl0 + r] = a;
        }
        load_pr3(l); load_wr3(l);
      }
      lbar();                                    // stage end
      if (orch) {
        if (lane < 4)
          gstore(&p.sxx[b * 4 + lane], sm[LX + b * 4 + lane] + sm[LRES + lane]);
        flag_pub(s);
        if (w2) {
#pragma unroll
          for (int c = 0; c < 4; ++c) {
            const int o = lane * 4 + c * 256;
            *(float4*)&p.out[OUT_SB + l * NEMBD + o] = *(float4*)&sm[LE + o];
            *(float4*)&p.out[OUT_SC + l * NEMBD + o] = *(float4*)&sm[LF + o];
          }
        }
        poll(s);
#pragma unroll
        for (int c = 0; c < 4; ++c) {
          const int o = lane * 4 + c * 256;
          *(float4*)&sm[LB + o] = make_float4(gload(&p.sxx[o]), gload(&p.sxx[o+1]),
                                              gload(&p.sxx[o+2]), gload(&p.sxx[o+3]));
        }
        load_pr3(l);
        post_gen(s + 1);
      }
    }

    // ================= STAGE 3: ln2 + masks + kffn/rffn GEMV =================
    {
      const unsigned s = (unsigned)(l * 4 + 3);
      if (!orch) spin_ge(s);
      float4 xv = *(const float4*)&sm[LB + i0];
      float xa[4] = {xv.x, xv.y, xv.z, xv.w};
      float m, rs; ln_stats(xa, m, rs);
#pragma unroll
      for (int j = 0; j < 4; ++j) {
        int i = i0 + j;
        float xx  = (xa[j] - m) * rs * fcomp(pr[0], j) + fcomp(pr[1], j);
        float sdv = fcomp(pr[2], j);
        sm[LD + i]        = xx + fcomp(pr[3], j) * sdv;
        sm[LD + 1024 + i] = xx + fcomp(pr[4], j) * sdv;
        if (w3) sm[LE + i] = xx;
      }
      lbar();
      if (!orch) {
#pragma unroll
        for (int e = 0; e < 7; ++e) {
          const int sidx = cw * 7 + e;
          if (sidx < 20) {
            const int mb = (sidx < 16) ? LD : LD + 1024;
            float a = 0.f;
#pragma unroll
            for (int jj = 0; jj < 4; ++jj)
              a += dot4(wr[e * 4 + jj], *(const float4*)&sm[mb + lane * 4 + jj * 256]);
            a = wred(a);
            if (lane == 0) {
              if (sidx < 16) { float kk = fmaxf(a, 0.f); sm[LRES + sidx] = kk * kk; }
              else { float ex = expf(a); sm[LRES + 16 + (sidx - 16)] = ex; sm[LRFB + (sidx - 16)] = ex; }
            }
          }
        }
        load_wr4(l);
      }
      lbar();                                    // stage end
      if (orch) {
        if (lane < 16) gstore(&p.kfb[b * 16 + lane], sm[LRES + lane]);
        if (lane < 4)  gstore(&p.rfb[b * 4 + lane],  sm[LRES + 16 + lane]);
        flag_pub(s);
        if (w3) {
#pragma unroll
          for (int c = 0; c < 4; ++c)
            *(float4*)&p.out[OUT_SD + l * NEMBD + lane * 4 + c * 256] =
              *(float4*)&sm[LE + lane * 4 + c * 256];
        }
        poll(s);
#pragma unroll
        for (int c = 0; c < 16; ++c) {
          const int o = lane * 4 + c * 256;
          *(float4*)&sm[LA + o] = make_float4(gload(&p.kfb[o]), gload(&p.kfb[o+1]),
                                              gload(&p.kfb[o+2]), gload(&p.kfb[o+3]));
        }
        post_gen(s + 1);
      }
    }

    // ================= STAGE 4: vffn GEMV (K-split) + x update =================
    {
      const unsigned s = (unsigned)(l * 4 + 4);
      if (!orch) {
        spin_ge(s);
        const int jbase = (cw == 0) ? 0 : ((cw == 1) ? 6 : 11);
        const int jn    = (cw == 0) ? 6 : 5;
#pragma unroll
        for (int r = 0; r < 4; ++r) {
          float a = 0.f;
#pragma unroll
          for (int c = 0; c < 6; ++c) if (c < jn)
            a += dot4(wr[r * 6 + c], *(const float4*)&sm[LA + lane * 4 + (jbase + c) * 256]);
          a = wred(a);
          if (lane == 0) sm[LRES + r * 3 + cw] = a;
        }
        if (l < NLAYER - 1) { load_pr1(l + 1); load_wr1(l + 1); }
      }
      lbar();                                    // stage end
      if (orch) {
        if (l == NLAYER - 1) {
          if (lane < 4) {
            float tot = sm[LRES + lane*3] + sm[LRES + lane*3 + 1] + sm[LRES + lane*3 + 2];
            p.out[b * 4 + lane] = sm[LB + b * 4 + lane] + tot / (sm[LRFB + lane] + 1.f);
          }
        } else {
          if (lane < 4) {
            float tot = sm[LRES + lane*3] + sm[LRES + lane*3 + 1] + sm[LRES + lane*3 + 2];
            float xn = sm[LB + b * 4 + lane] + tot / (sm[LRFB + lane] + 1.f);
            gstore(&p.xbuf[b * 4 + lane], xn);
          }
          flag_pub(s);
          poll(s);
#pragma unroll
          for (int c = 0; c < 4; ++c) {
            const int o = lane * 4 + c * 256;
            *(float4*)&sm[LX + o] = make_float4(gload(&p.xbuf[o]), gload(&p.xbuf[o+1]),
                                                gload(&p.xbuf[o+2]), gload(&p.xbuf[o+3]));
          }
          load_pr1(l + 1);
          post_gen(s + 1);
        }
      }
    }
  }
}

__global__ void rwkv_init(unsigned* flags) {
  flags[threadIdx.x * FLAG_STRIDE] = 0u;
}

extern "C" void kernel_launch(void* const* d_in, const int* in_sizes, int n_in,
                              void* d_out, int out_size, void* d_ws, size_t ws_size,
                              hipStream_t stream) {
  Params p;
  p.x       = (const float*)d_in[0];
  p.state   = (const float*)d_in[1];
  p.ln1w    = (const float*)d_in[2];
  p.ln1b    = (const float*)d_in[3];
  p.ln2w    = (const float*)d_in[4];
  p.ln2b    = (const float*)d_in[5];
  p.td      = (const float*)d_in[6];
  p.tf      = (const float*)d_in[7];
  p.kktk    = (const float*)d_in[8];
  p.vvtv    = (const float*)d_in[9];
  p.rrtr    = (const float*)d_in[10];
  p.key     = (const float*)d_in[11];
  p.outputv = (const float*)d_in[12];
  p.tmk     = (const float*)d_in[13];
  p.tmr     = (const float*)d_in[14];
  p.kffn    = (const float*)d_in[15];
  p.rffn    = (const float*)d_in[16];
  p.vffn    = (const float*)d_in[17];
  p.out     = (float*)d_out;

  float* ws = (float*)d_ws;
  p.xbuf = ws;                       // [1024]
  p.kvr  = ws + NEMBD;               // [3*1024]
  p.sxx  = ws + 4 * NEMBD;           // [1024]
  p.rfb  = ws + 5 * NEMBD;           // [1024]
  p.kfb  = ws + 6 * NEMBD;           // [4096]
  p.flags = (unsigned*)((char*)d_ws + 49152);   // 256 x 128B

  rwkv_init<<<1, NB, 0, stream>>>(p.flags);
  rwkv_persistent<<<NB, NT, 0, stream>>>(p);
}

// Round 8
// 582.733 us; speedup vs baseline: 1.4770x; 1.4770x over previous
//
#include <hip/hip_runtime.h>
#include <math.h>
#include <stddef.h>

#define NLAYER 24
#define NEMBD  1024
#define NFFN   4096
#define NB     256
#define NT     256          // 4 waves; wave 0 polls, waves 1-3 LDS-spin
#define NWC    4
#define LN_EPS 1e-5f

#define OUT_SA (NEMBD)
#define OUT_SB (NEMBD + NLAYER*NEMBD)
#define OUT_SC (NEMBD + 2*NLAYER*NEMBD)
#define OUT_SD (NEMBD + 3*NLAYER*NEMBD)

#define FLAG_STRIDE 32   // 32 u32 = 128 B per block flag line

struct Params {
  const float *x, *state, *ln1w, *ln1b, *ln2w, *ln2b, *td, *tf, *kktk, *vvtv, *rrtr;
  const float *key, *outputv, *tmk, *tmr, *kffn, *rffn, *vffn;
  float *out;
  float *xbuf, *kvr, *sxx, *rfb, *kfb;
  unsigned *flags, *geng;
};

__device__ __forceinline__ float wred(float v) {
#pragma unroll
  for (int o = 32; o > 0; o >>= 1) v += __shfl_xor(v, o, 64);
  return v;
}

__device__ __forceinline__ float dot4(float4 a, float4 b) {
  return a.x*b.x + a.y*b.y + a.z*b.z + a.w*b.w;
}

// Cross-block data ops: relaxed agent-scope atomics -> sc1 global ops that
// bypass the non-coherent XCD L2 and hit the LLC directly. No wbl2/inv.
__device__ __forceinline__ float gload(const float* a) {
  return __hip_atomic_load(a, __ATOMIC_RELAXED, __HIP_MEMORY_SCOPE_AGENT);
}
__device__ __forceinline__ void gstore(float* a, float v) {
  __hip_atomic_store(a, v, __ATOMIC_RELAXED, __HIP_MEMORY_SCOPE_AGENT);
}
__device__ __forceinline__ unsigned guload(const unsigned* a) {
  return __hip_atomic_load(a, __ATOMIC_RELAXED, __HIP_MEMORY_SCOPE_AGENT);
}
__device__ __forceinline__ void gustore(unsigned* a, unsigned v) {
  __hip_atomic_store(a, v, __ATOMIC_RELAXED, __HIP_MEMORY_SCOPE_AGENT);
}

// arrive: __syncthreads drains this block's vmem (data stores at LLC), then
// thread 0 publishes flag[b]=tgt.
__device__ __forceinline__ void bar_flag(unsigned* flags, unsigned tgt) {
  __syncthreads();
  if (threadIdx.x == 0) {
    gustore(&flags[(unsigned)blockIdx.x * FLAG_STRIDE], tgt);
  }
}

// Two-hop low-traffic spin:
//  - block 0 / wave 0 (aggregator): polls all 256 flags (4/lane), publishes a
//    single global gen word + LDS broadcast.
//  - wave 0 of other blocks: polls the ONE gen line (uniform address -> one
//    transaction per block per iteration), posts LDS genw.
//  - waves 1-3 everywhere: spin on LDS only; their global weight prefetch
//    stays in flight across the whole wait.
__device__ __forceinline__ void bar_spin(unsigned* flags, unsigned* geng,
                                         unsigned tgt, volatile unsigned* genw) {
  const int wid  = threadIdx.x >> 6;
  const int lane = threadIdx.x & 63;
  if (wid == 0) {
    if (blockIdx.x == 0) {
      long c = 0;
      for (;;) {
        bool mine = true;
#pragma unroll
        for (int j = 0; j < 4; ++j) {
          unsigned f = guload(&flags[(unsigned)(lane * 4 + j) * FLAG_STRIDE]);
          mine &= (f >= tgt);
        }
        if (__all(mine)) break;
        __builtin_amdgcn_s_sleep(1);
        if (++c > (1L << 18)) break;   // safety valve: wrong beats hang
      }
      if (lane == 0) gustore(geng, tgt);
    } else {
      long c = 0;
      while (guload(geng) < tgt) {
        __builtin_amdgcn_s_sleep(1);
        if (++c > (1L << 18)) break;
      }
    }
    if (lane == 0) *genw = tgt;
  } else {
    long c = 0;
    while (*genw < tgt) {
      __builtin_amdgcn_s_sleep(1);
      if (++c > (1L << 20)) break;
    }
  }
  asm volatile("" ::: "memory");
}

__global__ void __launch_bounds__(NT, 1)
rwkv_persistent(Params p) {
  const int b    = blockIdx.x;
  const int t    = threadIdx.x;
  const int wid  = t >> 6;
  const int lane = t & 63;

  __shared__ float lds[NFFN];
  __shared__ float reda[NWC], redq[NWC];
  __shared__ float mrs[2];
  __shared__ unsigned genw_s;
  volatile unsigned* genw = &genw_s;

  if (t == 0) genw_s = 0u;
  __syncthreads();

  float4 wr[20];                 // cross-barrier weight prefetch registers
  unsigned g = 1;

  // ---- prefetch lambdas (weights only; no barrier-data dependence) ----
  auto pf1 = [&](int layer) {
    const float* W = p.key + (size_t)layer * 3 * NEMBD * NEMBD
                   + (size_t)(b * 12 + wid * 3) * NEMBD + lane * 4;
#pragma unroll
    for (int r = 0; r < 3; ++r)
#pragma unroll
      for (int jj = 0; jj < 4; ++jj)
        wr[r * 4 + jj] = *(const float4*)&W[(size_t)r * NEMBD + jj * 256];
  };
  const int rowq = b * 4 + wid;            // stage-2/4 output row
  auto pf2 = [&](int layer) {
    const float* W = p.outputv + ((size_t)layer * NEMBD + rowq) * NEMBD + lane * 4;
#pragma unroll
    for (int jj = 0; jj < 4; ++jj)
      wr[jj] = *(const float4*)&W[jj * 256];
  };
  auto pf4 = [&](int layer) {
    const float* W = p.vffn + ((size_t)layer * NEMBD + rowq) * NFFN + lane * 4;
#pragma unroll
    for (int jj = 0; jj < 16; ++jj)
      wr[jj] = *(const float4*)&W[jj * 256];
  };

  // stage-3 row metadata (layer-independent)
  int isk3[5], rid3[5], voff3[5];
#pragma unroll
  for (int sI = 0; sI < 5; ++sI) {
    int qI = wid * 5 + sI;
    if (qI < 16) { isk3[sI] = 1; rid3[sI] = b * 16 + qI;       voff3[sI] = 0; }
    else         { isk3[sI] = 0; rid3[sI] = b * 4 + (qI - 16); voff3[sI] = NEMBD; }
  }
  auto pf3 = [&](int layer) {
#pragma unroll
    for (int sI = 0; sI < 5; ++sI) {
      const float* wp = isk3[sI]
        ? p.kffn + ((size_t)layer * NFFN  + rid3[sI]) * NEMBD
        : p.rffn + ((size_t)layer * NEMBD + rid3[sI]) * NEMBD;
      wp += lane * 4;
#pragma unroll
      for (int jj = 0; jj < 4; ++jj)
        wr[sI * 4 + jj] = *(const float4*)&wp[jj * 256];
    }
  };

  pf1(0);   // all waves prefetch layer-0 stage-1 weights (no barrier before it)

  for (int l = 0; l < NLAYER; ++l) {
    // distinct writer block per layer-stage for the state outputs
    const bool w1 = (b == (l * 4 + 0) % NB);   // statea (xy)
    const bool w2 = (b == (l * 4 + 1) % NB);   // stateb/statec
    const bool w3 = (b == (l * 4 + 2) % NB);   // stated (xx)

    // ================= stage 1: ln1 + k/v/r GEMV =================
    {
      const int i0 = t * 4;
      float xa[4];
      if (l == 0) {
        float4 x4 = *(const float4*)&p.x[i0];
        xa[0] = x4.x; xa[1] = x4.y; xa[2] = x4.z; xa[3] = x4.w;
      } else {
#pragma unroll
        for (int j = 0; j < 4; ++j) xa[j] = gload(&p.xbuf[i0 + j]);
      }
      float s = xa[0] + xa[1] + xa[2] + xa[3];
      float q = xa[0]*xa[0] + xa[1]*xa[1] + xa[2]*xa[2] + xa[3]*xa[3];
      s = wred(s); q = wred(q);
      if (lane == 0) { reda[wid] = s; redq[wid] = q; }
      __syncthreads();
      if (t == 0) {
        float ts = 0.f, tq = 0.f;
#pragma unroll
        for (int i = 0; i < NWC; ++i) { ts += reda[i]; tq += redq[i]; }
        float m = ts * (1.f / NEMBD);
        float var = tq * (1.f / NEMBD) - m * m;
        mrs[0] = m; mrs[1] = rsqrtf(var + LN_EPS);
      }
      __syncthreads();
      float m = mrs[0], rs = mrs[1];
      const float* l1w = p.ln1w + l * NEMBD;
      const float* l1b = p.ln1b + l * NEMBD;
      const float* sa  = p.state + 0 * NLAYER * NEMBD + l * NEMBD;
      const float* kkp = p.kktk + l * NEMBD;
      const float* vvp = p.vvtv + l * NEMBD;
      const float* rrp = p.rrtr + l * NEMBD;
#pragma unroll
      for (int j = 0; j < 4; ++j) {
        int i = i0 + j;
        float xy = (xa[j] - m) * rs * l1w[i] + l1b[i];
        float sav = sa[i];
        lds[i]             = xy + kkp[i] * sav;
        lds[NEMBD + i]     = xy + vvp[i] * sav;
        lds[2 * NEMBD + i] = xy + rrp[i] * sav;
        if (w1) p.out[OUT_SA + l * NEMBD + i] = xy;   // statea_new
      }
      __syncthreads();

      const int r0 = b * 12 + wid * 3;   // 3072 rows over 1024 waves
      const float* v0 = lds + ((r0 + 0) >> 10) * NEMBD;
      const float* v1 = lds + ((r0 + 1) >> 10) * NEMBD;
      const float* v2 = lds + ((r0 + 2) >> 10) * NEMBD;
      float a0 = 0.f, a1 = 0.f, a2 = 0.f;
#pragma unroll
      for (int jj = 0; jj < 4; ++jj) {
        int col = lane * 4 + jj * 256;
        a0 += dot4(wr[0 * 4 + jj], *(const float4*)&v0[col]);
        a1 += dot4(wr[1 * 4 + jj], *(const float4*)&v1[col]);
        a2 += dot4(wr[2 * 4 + jj], *(const float4*)&v2[col]);
      }
      a0 = wred(a0); a1 = wred(a1); a2 = wred(a2);
      if (lane == 0) {
        gstore(&p.kvr[r0 + 0], a0);
        gstore(&p.kvr[r0 + 1], a1);
        gstore(&p.kvr[r0 + 2], a2);
      }
    }
    bar_flag(p.flags, g);
    pf2(l);                            // in flight across the spin
    bar_spin(p.flags, p.geng, g, genw); ++g;

    // ================= stage 2: wkv combine + outputv GEMV + state out ====
    {
      const int i0 = t * 4;
      const float* tfp = p.tf + l * NEMBD;
      const float* sbp = p.state + 1 * NLAYER * NEMBD + l * NEMBD;
      const float* scp = p.state + 2 * NLAYER * NEMBD + l * NEMBD;
      const float* tdp = p.td + l * NEMBD;
#pragma unroll
      for (int j = 0; j < 4; ++j) {
        int i = i0 + j;
        float k = gload(&p.kvr[i]);
        float v = gload(&p.kvr[NEMBD + i]);
        float r = gload(&p.kvr[2 * NEMBD + i]);
        float sb = sbp[i], sc = scp[i];
        float etfk = expf(tfp[i] + k);
        float er   = expf(r);
        // sc*er + exp(tf+k+r) + sc + etfk == (sc+etfk)*(1+er)
        lds[i] = (sb + etfk * v) / ((sc + etfk) * (1.f + er));
        if (w2) {
          float ek = expf(k), ed = expf(tdp[i]);
          p.out[OUT_SB + l * NEMBD + i] = sb * ed + ek * v;
          p.out[OUT_SC + l * NEMBD + i] = sc * ed + ek;
        }
      }
      __syncthreads();
      float acc = 0.f;
#pragma unroll
      for (int jj = 0; jj < 4; ++jj) {
        int col = lane * 4 + jj * 256;
        acc += dot4(wr[jj], *(const float4*)&lds[col]);
      }
      acc = wred(acc);
      if (lane == 0) {
        float xc = (l == 0) ? p.x[rowq] : gload(&p.xbuf[rowq]);
        gstore(&p.sxx[rowq], xc + acc);
      }
    }
    bar_flag(p.flags, g);
    pf3(l);
    bar_spin(p.flags, p.geng, g, genw); ++g;

    // ================= stage 3: ln2 + key_ffn / receptance_ffn GEMV =======
    {
      const int i0 = t * 4;
      float xa[4];
#pragma unroll
      for (int j = 0; j < 4; ++j) xa[j] = gload(&p.sxx[i0 + j]);
      float s = xa[0] + xa[1] + xa[2] + xa[3];
      float q = xa[0]*xa[0] + xa[1]*xa[1] + xa[2]*xa[2] + xa[3]*xa[3];
      s = wred(s); q = wred(q);
      if (lane == 0) { reda[wid] = s; redq[wid] = q; }
      __syncthreads();
      if (t == 0) {
        float ts = 0.f, tq = 0.f;
#pragma unroll
        for (int i = 0; i < NWC; ++i) { ts += reda[i]; tq += redq[i]; }
        float m = ts * (1.f / NEMBD);
        float var = tq * (1.f / NEMBD) - m * m;
        mrs[0] = m; mrs[1] = rsqrtf(var + LN_EPS);
      }
      __syncthreads();
      float m = mrs[0], rs = mrs[1];
      const float* l2w = p.ln2w + l * NEMBD;
      const float* l2b = p.ln2b + l * NEMBD;
      const float* sdp = p.state + 3 * NLAYER * NEMBD + l * NEMBD;
      const float* tmkp = p.tmk + l * NEMBD;
      const float* tmrp = p.tmr + l * NEMBD;
#pragma unroll
      for (int j = 0; j < 4; ++j) {
        int i = i0 + j;
        float xx = (xa[j] - m) * rs * l2w[i] + l2b[i];
        float sdv = sdp[i];
        lds[i]         = xx + tmkp[i] * sdv;
        lds[NEMBD + i] = xx + tmrp[i] * sdv;
        if (w3) p.out[OUT_SD + l * NEMBD + i] = xx;   // stated_new
      }
      __syncthreads();

      float acc[5] = {0.f, 0.f, 0.f, 0.f, 0.f};
#pragma unroll
      for (int jj = 0; jj < 4; ++jj) {
        int col = lane * 4 + jj * 256;
#pragma unroll
        for (int sI = 0; sI < 5; ++sI)
          acc[sI] += dot4(wr[sI * 4 + jj], *(const float4*)&lds[voff3[sI] + col]);
      }
#pragma unroll
      for (int sI = 0; sI < 5; ++sI) {
        float r = wred(acc[sI]);
        if (lane == 0) {
          if (isk3[sI]) { float kv = fmaxf(r, 0.f); gstore(&p.kfb[rid3[sI]], kv * kv); }
          else          { gstore(&p.rfb[rid3[sI]], expf(r)); }
        }
      }
    }
    bar_flag(p.flags, g);
    pf4(l);
    bar_spin(p.flags, p.geng, g, genw); ++g;

    // ================= stage 4: value_ffn GEMV + x update =================
    {
#pragma unroll
      for (int pass = 0; pass < 4; ++pass) {
        int idx = pass * NEMBD + t * 4;
        float a0 = gload(&p.kfb[idx + 0]);
        float a1 = gload(&p.kfb[idx + 1]);
        float a2 = gload(&p.kfb[idx + 2]);
        float a3 = gload(&p.kfb[idx + 3]);
        *(float4*)&lds[idx] = make_float4(a0, a1, a2, a3);
      }
      __syncthreads();
      float accA = 0.f, accB = 0.f;
#pragma unroll
      for (int jj = 0; jj < 16; jj += 2) {
        int col = lane * 4 + jj * 256;
        accA += dot4(wr[jj],     *(const float4*)&lds[col]);
        accB += dot4(wr[jj + 1], *(const float4*)&lds[col + 256]);
      }
      float acc = wred(accA + accB);
      if (lane == 0) {
        float xn = gload(&p.sxx[rowq]) + acc / (gload(&p.rfb[rowq]) + 1.f);
        if (l == NLAYER - 1) p.out[rowq] = xn;     // final x_out
        else                 gstore(&p.xbuf[rowq], xn);
      }
    }
    if (l < NLAYER - 1) {
      bar_flag(p.flags, g);
      pf1(l + 1);
      bar_spin(p.flags, p.geng, g, genw); ++g;
    }
  }
}

__global__ void rwkv_init(unsigned* flags, unsigned* geng) {
  flags[threadIdx.x * FLAG_STRIDE] = 0u;
  if (threadIdx.x == 0) *geng = 0u;
}

extern "C" void kernel_launch(void* const* d_in, const int* in_sizes, int n_in,
                              void* d_out, int out_size, void* d_ws, size_t ws_size,
                              hipStream_t stream) {
  Params p;
  p.x       = (const float*)d_in[0];
  p.state   = (const float*)d_in[1];
  p.ln1w    = (const float*)d_in[2];
  p.ln1b    = (const float*)d_in[3];
  p.ln2w    = (const float*)d_in[4];
  p.ln2b    = (const float*)d_in[5];
  p.td      = (const float*)d_in[6];
  p.tf      = (const float*)d_in[7];
  p.kktk    = (const float*)d_in[8];
  p.vvtv    = (const float*)d_in[9];
  p.rrtr    = (const float*)d_in[10];
  p.key     = (const float*)d_in[11];
  p.outputv = (const float*)d_in[12];
  p.tmk     = (const float*)d_in[13];
  p.tmr     = (const float*)d_in[14];
  p.kffn    = (const float*)d_in[15];
  p.rffn    = (const float*)d_in[16];
  p.vffn    = (const float*)d_in[17];
  p.out     = (float*)d_out;

  float* ws = (float*)d_ws;
  p.xbuf = ws;                       // [1024]
  p.kvr  = ws + NEMBD;               // [3*1024]
  p.sxx  = ws + 4 * NEMBD;           // [1024]
  p.rfb  = ws + 5 * NEMBD;           // [1024]
  p.kfb  = ws + 6 * NEMBD;           // [4096]   -> ends at byte 40960
  p.flags = (unsigned*)((char*)d_ws + 49152);   // 256 x 128B = 32 KiB
  p.geng  = (unsigned*)((char*)d_ws + 49152 + 256 * FLAG_STRIDE * 4 + 128);

  rwkv_init<<<1, NB, 0, stream>>>(p.flags, p.geng);
  rwkv_persistent<<<NB, NT, 0, stream>>>(p);
}